// Round 1
// baseline (731.007 us; speedup 1.0000x reference)
//
#include <hip/hip_runtime.h>
#include <math.h>

#define NEG_SLOPE 0.2f

// ---------------- CSR build ----------------

__global__ void zero_deg_kernel(int* __restrict__ deg, int n) {
    int i = blockIdx.x * blockDim.x + threadIdx.x;
    if (i < n) deg[i] = 0;
}

__global__ void hist_kernel(const int* __restrict__ dst, int* __restrict__ deg, int E) {
    int i = blockIdx.x * blockDim.x + threadIdx.x;
    if (i < E) atomicAdd(&deg[dst[i]], 1);
}

__global__ __launch_bounds__(1024) void scan_kernel(const int* __restrict__ deg,
                                                    int* __restrict__ off,
                                                    int* __restrict__ cursor, int n) {
    __shared__ int sums[1024];
    int t = threadIdx.x;
    int per = (n + 1023) / 1024;
    int start = t * per;
    int s = 0;
    for (int i = 0; i < per; ++i) {
        int idx = start + i;
        if (idx < n) s += deg[idx];
    }
    sums[t] = s;
    __syncthreads();
    // Hillis-Steele inclusive scan over 1024 partial sums
    for (int o = 1; o < 1024; o <<= 1) {
        int v = (t >= o) ? sums[t - o] : 0;
        __syncthreads();
        sums[t] += v;
        __syncthreads();
    }
    int run = (t == 0) ? 0 : sums[t - 1];
    for (int i = 0; i < per; ++i) {
        int idx = start + i;
        if (idx < n) {
            int d = deg[idx];
            off[idx] = run;
            cursor[idx] = run;
            run += d;
        }
    }
    if (t == 1023) off[n] = sums[1023];
}

__global__ void scatter_kernel(const int* __restrict__ src, const int* __restrict__ dst,
                               int* __restrict__ cursor, int* __restrict__ csr_src, int E) {
    int i = blockIdx.x * blockDim.x + threadIdx.x;
    if (i < E) {
        int d = dst[i];
        int p = atomicAdd(&cursor[d], 1);
        csr_src[p] = src[i];
    }
}

// ---------------- GEMM + alpha epilogue ----------------
// block = 256 threads = 4 waves; one wave per node, lane = output channel (cout=64).
// W (cin x 64) staged in LDS; h row staged in LDS; fused alpha_src/alpha_dst dot via
// wave shuffle reduction.

__global__ __launch_bounds__(256) void gemm_alpha_kernel(
        const float* __restrict__ h, const float* __restrict__ W,
        const float* __restrict__ a_src, const float* __restrict__ a_dst,
        float* __restrict__ hp, float* __restrict__ as_, float* __restrict__ ad_,
        int n, int cin) {
    extern __shared__ float smem[];
    float* Ws = smem;              // cin * 64
    float* hs = smem + cin * 64;   // 4 * cin
    int t = threadIdx.x;
    int wave = t >> 6, lane = t & 63;
    int node = blockIdx.x * 4 + wave;

    for (int i = t; i < cin * 64; i += 256) Ws[i] = W[i];
    if (node < n) {
        for (int k = lane; k < cin; k += 64) hs[wave * cin + k] = h[(size_t)node * cin + k];
    }
    __syncthreads();
    if (node >= n) return;

    const float* hrow = hs + wave * cin;
    float acc = 0.f;
#pragma unroll 8
    for (int k = 0; k < cin; ++k) acc = fmaf(hrow[k], Ws[k * 64 + lane], acc);

    hp[(size_t)node * 64 + lane] = acc;

    float vs = acc * a_src[lane];
    float vd = acc * a_dst[lane];
#pragma unroll
    for (int o = 32; o > 0; o >>= 1) {
        vs += __shfl_down(vs, o);
        vd += __shfl_down(vd, o);
    }
    if (lane == 0) {
        as_[node] = vs;
        ad_[node] = vd;
    }
}

// ---------------- per-dst segment softmax + weighted gather-sum ----------------
// one wave per destination node; self-loop handled analytically.

__global__ __launch_bounds__(256) void agg_kernel(
        const float* __restrict__ hp,
        const float* __restrict__ as_, const float* __restrict__ ad_,
        const int* __restrict__ off, const int* __restrict__ csr_src,
        const float* __restrict__ bias, float* __restrict__ out, int n) {
    int t = threadIdx.x;
    int wave = t >> 6, lane = t & 63;
    int node = blockIdx.x * 4 + wave;
    if (node >= n) return;

    int beg = off[node], end = off[node + 1];
    float adst = ad_[node];

    // self-loop logit
    float e_self = as_[node] + adst;
    e_self = e_self > 0.f ? e_self : NEG_SLOPE * e_self;

    // phase A1: lane-parallel max over incoming edges
    float mymax = e_self;
    for (int i = beg + lane; i < end; i += 64) {
        int s = csr_src[i];
        float e = as_[s] + adst;
        e = e > 0.f ? e : NEG_SLOPE * e;
        mymax = fmaxf(mymax, e);
    }
#pragma unroll
    for (int o = 32; o > 0; o >>= 1) mymax = fmaxf(mymax, __shfl_xor(mymax, o));
    float m = mymax;

    // phase A2: lane-parallel sum of exp(e - m)
    float se = 0.f;
    for (int i = beg + lane; i < end; i += 64) {
        int s = csr_src[i];
        float e = as_[s] + adst;
        e = e > 0.f ? e : NEG_SLOPE * e;
        se += expf(e - m);
    }
#pragma unroll
    for (int o = 32; o > 0; o >>= 1) se += __shfl_xor(se, o);
    se += expf(e_self - m);  // identical on all lanes
    float inv = 1.0f / (se + 1e-16f);

    // phase B: serial over edges, lanes = 64 channels
    float acc = expf(e_self - m) * inv * hp[(size_t)node * 64 + lane];
    for (int i = beg; i < end; ++i) {
        int s = csr_src[i];                 // broadcast load
        float e = as_[s] + adst;            // broadcast load
        e = e > 0.f ? e : NEG_SLOPE * e;
        float w = expf(e - m) * inv;
        acc = fmaf(w, hp[(size_t)s * 64 + lane], acc);
    }
    float r = acc + bias[lane];
    out[(size_t)node * 64 + lane] = r > 0.f ? r : 0.f;
}

// ---------------- launch ----------------

extern "C" void kernel_launch(void* const* d_in, const int* in_sizes, int n_in,
                              void* d_out, int out_size, void* d_ws, size_t ws_size,
                              hipStream_t stream) {
    const float* x = (const float*)d_in[0];
    const int* edge_index = (const int*)d_in[1];
    const int N = in_sizes[0] / 128;
    const int E = in_sizes[1] / 2;

    const float* W[3]    = {(const float*)d_in[4], (const float*)d_in[8],  (const float*)d_in[12]};
    const float* asrc[3] = {(const float*)d_in[5], (const float*)d_in[9],  (const float*)d_in[13]};
    const float* adst[3] = {(const float*)d_in[6], (const float*)d_in[10], (const float*)d_in[14]};
    const float* bias[3] = {(const float*)d_in[7], (const float*)d_in[11], (const float*)d_in[15]};
    const int cin[3] = {128, 64, 64};

    char* ws = (char*)d_ws;
    size_t o = 0;
    auto alloc = [&](size_t bytes) {
        char* p = ws + o;
        o += (bytes + 255) & ~(size_t)255;
        return p;
    };
    int* deg      = (int*)alloc((size_t)N * 4);
    int* off      = (int*)alloc((size_t)(N + 1) * 4);
    int* cursor   = (int*)alloc((size_t)N * 4);
    int* csr_src  = (int*)alloc((size_t)E * 4);
    float* as_    = (float*)alloc((size_t)N * 4);
    float* ad_    = (float*)alloc((size_t)N * 4);
    float* bufA   = (float*)alloc((size_t)N * 64 * 4);
    float* bufB   = (float*)alloc((size_t)N * 64 * 4);

    const int* srcp = edge_index;
    const int* dstp = edge_index + E;

    zero_deg_kernel<<<(N + 255) / 256, 256, 0, stream>>>(deg, N);
    hist_kernel<<<(E + 255) / 256, 256, 0, stream>>>(dstp, deg, E);
    scan_kernel<<<1, 1024, 0, stream>>>(deg, off, cursor, N);
    scatter_kernel<<<(E + 255) / 256, 256, 0, stream>>>(srcp, dstp, cursor, csr_src, E);

    const float* hin = x;
    for (int l = 0; l < 3; ++l) {
        float* hp = bufA;
        float* hout = (l == 2) ? (float*)d_out : bufB;
        size_t smem = (size_t)(cin[l] * 64 + 4 * cin[l]) * sizeof(float);
        gemm_alpha_kernel<<<(N + 3) / 4, 256, smem, stream>>>(
            hin, W[l], asrc[l], adst[l], hp, as_, ad_, N, cin[l]);
        agg_kernel<<<(N + 3) / 4, 256, 0, stream>>>(
            hp, as_, ad_, off, csr_src, bias[l], hout, N);
        hin = hout;
    }
}

// Round 2
// 603.030 us; speedup vs baseline: 1.2122x; 1.2122x over previous
//
#include <hip/hip_runtime.h>
#include <math.h>

#define NEG_SLOPE 0.2f
#define SCAN_BLOCK 512

// ---------------- CSR build ----------------

__global__ void hist_kernel(const int* __restrict__ dst, int* __restrict__ deg, int E) {
    int i = blockIdx.x * blockDim.x + threadIdx.x;
    if (i < E) atomicAdd(&deg[dst[i]], 1);
}

// Stage A: per-block reduce of deg -> blockSums[b]
__global__ __launch_bounds__(SCAN_BLOCK) void block_reduce_kernel(
        const int* __restrict__ deg, int* __restrict__ blockSums, int n) {
    __shared__ int ws[SCAN_BLOCK / 64];
    int t = threadIdx.x;
    int i = blockIdx.x * SCAN_BLOCK + t;
    int v = (i < n) ? deg[i] : 0;
#pragma unroll
    for (int o = 32; o > 0; o >>= 1) v += __shfl_down(v, o);
    if ((t & 63) == 0) ws[t >> 6] = v;
    __syncthreads();
    if (t == 0) {
        int s = 0;
#pragma unroll
        for (int j = 0; j < SCAN_BLOCK / 64; ++j) s += ws[j];
        blockSums[blockIdx.x] = s;
    }
}

// Stage B: single small block scans the (<=256) block sums -> exclusive blockOff;
// also writes off[n] = total.
__global__ __launch_bounds__(256) void scan_sums_kernel(
        const int* __restrict__ blockSums, int* __restrict__ blockOff,
        int* __restrict__ off, int n, int nb) {
    __shared__ int s[256];
    int t = threadIdx.x;
    int v = (t < nb) ? blockSums[t] : 0;
    s[t] = v;
    __syncthreads();
    for (int o = 1; o < 256; o <<= 1) {
        int x = (t >= o) ? s[t - o] : 0;
        __syncthreads();
        s[t] += x;
        __syncthreads();
    }
    if (t < nb) blockOff[t] = s[t] - v;   // exclusive
    if (t == nb - 1) off[n] = s[t];       // total edge count
}

// Stage C: per-block local exclusive scan + blockOff -> off/cursor
__global__ __launch_bounds__(SCAN_BLOCK) void write_offsets_kernel(
        const int* __restrict__ deg, const int* __restrict__ blockOff,
        int* __restrict__ off, int* __restrict__ cursor, int n) {
    __shared__ int s[SCAN_BLOCK];
    int t = threadIdx.x;
    int i = blockIdx.x * SCAN_BLOCK + t;
    int v = (i < n) ? deg[i] : 0;
    s[t] = v;
    __syncthreads();
    for (int o = 1; o < SCAN_BLOCK; o <<= 1) {
        int x = (t >= o) ? s[t - o] : 0;
        __syncthreads();
        s[t] += x;
        __syncthreads();
    }
    if (i < n) {
        int pos = blockOff[blockIdx.x] + s[t] - v;  // exclusive
        off[i] = pos;
        cursor[i] = pos;
    }
}

__global__ void scatter_kernel(const int* __restrict__ src, const int* __restrict__ dst,
                               int* __restrict__ cursor, int* __restrict__ csr_src, int E) {
    int i = blockIdx.x * blockDim.x + threadIdx.x;
    if (i < E) {
        int d = dst[i];
        int p = atomicAdd(&cursor[d], 1);
        csr_src[p] = src[i];
    }
}

// ---------------- GEMM + alpha epilogue ----------------
// block = 256 threads = 4 waves; one wave per node, lane = output channel (cout=64).

__global__ __launch_bounds__(256) void gemm_alpha_kernel(
        const float* __restrict__ h, const float* __restrict__ W,
        const float* __restrict__ a_src, const float* __restrict__ a_dst,
        float* __restrict__ hp, float* __restrict__ as_, float* __restrict__ ad_,
        int n, int cin) {
    extern __shared__ float smem[];
    float* Ws = smem;              // cin * 64
    float* hs = smem + cin * 64;   // 4 * cin
    int t = threadIdx.x;
    int wave = t >> 6, lane = t & 63;
    int node = blockIdx.x * 4 + wave;

    for (int i = t; i < cin * 64; i += 256) Ws[i] = W[i];
    if (node < n) {
        for (int k = lane; k < cin; k += 64) hs[wave * cin + k] = h[(size_t)node * cin + k];
    }
    __syncthreads();
    if (node >= n) return;

    const float* hrow = hs + wave * cin;
    float acc = 0.f;
#pragma unroll 8
    for (int k = 0; k < cin; ++k) acc = fmaf(hrow[k], Ws[k * 64 + lane], acc);

    hp[(size_t)node * 64 + lane] = acc;

    float vs = acc * a_src[lane];
    float vd = acc * a_dst[lane];
#pragma unroll
    for (int o = 32; o > 0; o >>= 1) {
        vs += __shfl_down(vs, o);
        vd += __shfl_down(vd, o);
    }
    if (lane == 0) {
        as_[node] = vs;
        ad_[node] = vd;
    }
}

// ---------------- per-dst segment softmax + weighted gather-sum ----------------

__global__ __launch_bounds__(256) void agg_kernel(
        const float* __restrict__ hp,
        const float* __restrict__ as_, const float* __restrict__ ad_,
        const int* __restrict__ off, const int* __restrict__ csr_src,
        const float* __restrict__ bias, float* __restrict__ out, int n) {
    int t = threadIdx.x;
    int wave = t >> 6, lane = t & 63;
    int node = blockIdx.x * 4 + wave;
    if (node >= n) return;

    int beg = off[node], end = off[node + 1];
    float adst = ad_[node];

    float e_self = as_[node] + adst;
    e_self = e_self > 0.f ? e_self : NEG_SLOPE * e_self;

    float mymax = e_self;
    for (int i = beg + lane; i < end; i += 64) {
        int s = csr_src[i];
        float e = as_[s] + adst;
        e = e > 0.f ? e : NEG_SLOPE * e;
        mymax = fmaxf(mymax, e);
    }
#pragma unroll
    for (int o = 32; o > 0; o >>= 1) mymax = fmaxf(mymax, __shfl_xor(mymax, o));
    float m = mymax;

    float se = 0.f;
    for (int i = beg + lane; i < end; i += 64) {
        int s = csr_src[i];
        float e = as_[s] + adst;
        e = e > 0.f ? e : NEG_SLOPE * e;
        se += expf(e - m);
    }
#pragma unroll
    for (int o = 32; o > 0; o >>= 1) se += __shfl_xor(se, o);
    se += expf(e_self - m);
    float inv = 1.0f / (se + 1e-16f);

    float acc = expf(e_self - m) * inv * hp[(size_t)node * 64 + lane];
    for (int i = beg; i < end; ++i) {
        int s = csr_src[i];
        float e = as_[s] + adst;
        e = e > 0.f ? e : NEG_SLOPE * e;
        float w = expf(e - m) * inv;
        acc = fmaf(w, hp[(size_t)s * 64 + lane], acc);
    }
    float r = acc + bias[lane];
    out[(size_t)node * 64 + lane] = r > 0.f ? r : 0.f;
}

// ---------------- launch ----------------

extern "C" void kernel_launch(void* const* d_in, const int* in_sizes, int n_in,
                              void* d_out, int out_size, void* d_ws, size_t ws_size,
                              hipStream_t stream) {
    const float* x = (const float*)d_in[0];
    const int* edge_index = (const int*)d_in[1];
    const int N = in_sizes[0] / 128;
    const int E = in_sizes[1] / 2;

    const float* W[3]    = {(const float*)d_in[4], (const float*)d_in[8],  (const float*)d_in[12]};
    const float* asrc[3] = {(const float*)d_in[5], (const float*)d_in[9],  (const float*)d_in[13]};
    const float* adst[3] = {(const float*)d_in[6], (const float*)d_in[10], (const float*)d_in[14]};
    const float* bias[3] = {(const float*)d_in[7], (const float*)d_in[11], (const float*)d_in[15]};
    const int cin[3] = {128, 64, 64};

    char* ws = (char*)d_ws;
    size_t o = 0;
    auto alloc = [&](size_t bytes) {
        char* p = ws + o;
        o += (bytes + 255) & ~(size_t)255;
        return p;
    };
    const int nb = (N + SCAN_BLOCK - 1) / SCAN_BLOCK;
    int* deg       = (int*)alloc((size_t)N * 4);
    int* off       = (int*)alloc((size_t)(N + 1) * 4);
    int* cursor    = (int*)alloc((size_t)N * 4);
    int* csr_src   = (int*)alloc((size_t)E * 4);
    int* blockSums = (int*)alloc((size_t)nb * 4);
    int* blockOff  = (int*)alloc((size_t)nb * 4);
    float* as_     = (float*)alloc((size_t)N * 4);
    float* ad_     = (float*)alloc((size_t)N * 4);
    float* bufA    = (float*)alloc((size_t)N * 64 * 4);
    float* bufB    = (float*)alloc((size_t)N * 64 * 4);

    const int* srcp = edge_index;
    const int* dstp = edge_index + E;

    hipMemsetAsync(deg, 0, (size_t)N * 4, stream);
    hist_kernel<<<(E + 255) / 256, 256, 0, stream>>>(dstp, deg, E);
    block_reduce_kernel<<<nb, SCAN_BLOCK, 0, stream>>>(deg, blockSums, N);
    scan_sums_kernel<<<1, 256, 0, stream>>>(blockSums, blockOff, off, N, nb);
    write_offsets_kernel<<<nb, SCAN_BLOCK, 0, stream>>>(deg, blockOff, off, cursor, N);
    scatter_kernel<<<(E + 255) / 256, 256, 0, stream>>>(srcp, dstp, cursor, csr_src, E);

    const float* hin = x;
    for (int l = 0; l < 3; ++l) {
        float* hp = bufA;
        float* hout = (l == 2) ? (float*)d_out : bufB;
        size_t smem = (size_t)(cin[l] * 64 + 4 * cin[l]) * sizeof(float);
        gemm_alpha_kernel<<<(N + 3) / 4, 256, smem, stream>>>(
            hin, W[l], asrc[l], adst[l], hp, as_, ad_, N, cin[l]);
        agg_kernel<<<(N + 3) / 4, 256, 0, stream>>>(
            hp, as_, ad_, off, csr_src, bias[l], hout, N);
        hin = hout;
    }
}

// Round 3
// 461.263 us; speedup vs baseline: 1.5848x; 1.3073x over previous
//
#include <hip/hip_runtime.h>
#include <math.h>

#define NEG_SLOPE 0.2f
#define SCAN_BLOCK 512

__device__ __forceinline__ float leaky(float e) {
    return e > 0.f ? e : NEG_SLOPE * e;
}
__device__ __forceinline__ float bcast(float v, int j) {
    return __uint_as_float(__builtin_amdgcn_readlane(__float_as_uint(v), j));
}
__device__ __forceinline__ int bcast_i(int v, int j) {
    return __builtin_amdgcn_readlane(v, j);
}

// ---------------- CSR build ----------------

__global__ void hist_kernel(const int* __restrict__ dst, int* __restrict__ deg, int E) {
    int i = blockIdx.x * blockDim.x + threadIdx.x;
    if (i < E) atomicAdd(&deg[dst[i]], 1);
}

__global__ __launch_bounds__(SCAN_BLOCK) void block_reduce_kernel(
        const int* __restrict__ deg, int* __restrict__ blockSums, int n) {
    __shared__ int ws[SCAN_BLOCK / 64];
    int t = threadIdx.x;
    int i = blockIdx.x * SCAN_BLOCK + t;
    int v = (i < n) ? deg[i] : 0;
#pragma unroll
    for (int o = 32; o > 0; o >>= 1) v += __shfl_down(v, o);
    if ((t & 63) == 0) ws[t >> 6] = v;
    __syncthreads();
    if (t == 0) {
        int s = 0;
#pragma unroll
        for (int j = 0; j < SCAN_BLOCK / 64; ++j) s += ws[j];
        blockSums[blockIdx.x] = s;
    }
}

__global__ __launch_bounds__(256) void scan_sums_kernel(
        const int* __restrict__ blockSums, int* __restrict__ blockOff,
        int* __restrict__ off, int n, int nb) {
    __shared__ int s[256];
    int t = threadIdx.x;
    int v = (t < nb) ? blockSums[t] : 0;
    s[t] = v;
    __syncthreads();
    for (int o = 1; o < 256; o <<= 1) {
        int x = (t >= o) ? s[t - o] : 0;
        __syncthreads();
        s[t] += x;
        __syncthreads();
    }
    if (t < nb) blockOff[t] = s[t] - v;
    if (t == nb - 1) off[n] = s[t];
}

__global__ __launch_bounds__(SCAN_BLOCK) void write_offsets_kernel(
        const int* __restrict__ deg, const int* __restrict__ blockOff,
        int* __restrict__ off, int* __restrict__ cursor, int n) {
    __shared__ int s[SCAN_BLOCK];
    int t = threadIdx.x;
    int i = blockIdx.x * SCAN_BLOCK + t;
    int v = (i < n) ? deg[i] : 0;
    s[t] = v;
    __syncthreads();
    for (int o = 1; o < SCAN_BLOCK; o <<= 1) {
        int x = (t >= o) ? s[t - o] : 0;
        __syncthreads();
        s[t] += x;
        __syncthreads();
    }
    if (i < n) {
        int pos = blockOff[blockIdx.x] + s[t] - v;
        off[i] = pos;
        cursor[i] = pos;
    }
}

__global__ void scatter_kernel(const int* __restrict__ src, const int* __restrict__ dst,
                               int* __restrict__ cursor, int* __restrict__ csr_src, int E) {
    int i = blockIdx.x * blockDim.x + threadIdx.x;
    if (i < E) {
        int d = dst[i];
        int p = atomicAdd(&cursor[d], 1);
        csr_src[p] = src[i];
    }
}

// ---------------- GEMM + alpha epilogue ----------------
// 8 nodes per wave, 32 nodes per block. W staged in LDS (read once per k for
// 8 FMAs); h rows preloaded into registers, broadcast via v_readlane (VALU
// pipe, not LDS). Templated on CIN so register arrays stay statically indexed.

template <int CIN>
__global__ __launch_bounds__(256) void gemm_alpha_kernel(
        const float* __restrict__ h, const float* __restrict__ W,
        const float* __restrict__ a_src, const float* __restrict__ a_dst,
        float* __restrict__ hp, float* __restrict__ as_, float* __restrict__ ad_,
        int n) {
    constexpr int NPW = 8;
    constexpr int NC = CIN / 64;
    __shared__ float Ws[CIN * 64];
    int t = threadIdx.x, wave = t >> 6, lane = t & 63;
    int node0 = blockIdx.x * 32 + wave * NPW;

    // stage W (CIN x 64 row-major) into LDS with float4 loads
    {
        const float4* W4 = (const float4*)W;
        float4* Ws4 = (float4*)Ws;
        constexpr int cnt = CIN * 16;
#pragma unroll
        for (int i = 0; i < cnt / 256; ++i) Ws4[i * 256 + t] = W4[i * 256 + t];
    }

    // preload h rows (coalesced 256B per row-chunk)
    float hreg[NPW][NC];
#pragma unroll
    for (int r = 0; r < NPW; ++r) {
        int node = node0 + r;
#pragma unroll
        for (int c = 0; c < NC; ++c)
            hreg[r][c] = (node < n) ? h[(size_t)node * CIN + c * 64 + lane] : 0.f;
    }
    __syncthreads();

    float acc[NPW];
#pragma unroll
    for (int r = 0; r < NPW; ++r) acc[r] = 0.f;

#pragma unroll
    for (int c = 0; c < NC; ++c) {
#pragma unroll 8
        for (int k2 = 0; k2 < 64; ++k2) {
            float w = Ws[(c * 64 + k2) * 64 + lane];
#pragma unroll
            for (int r = 0; r < NPW; ++r)
                acc[r] = fmaf(bcast(hreg[r][c], k2), w, acc[r]);
        }
    }

    float asl = a_src[lane], adl = a_dst[lane];
#pragma unroll
    for (int r = 0; r < NPW; ++r) {
        int node = node0 + r;
        if (node >= n) break;
        hp[(size_t)node * 64 + lane] = acc[r];
        float vs = acc[r] * asl;
        float vd = acc[r] * adl;
#pragma unroll
        for (int o = 32; o > 0; o >>= 1) {
            vs += __shfl_xor(vs, o);
            vd += __shfl_xor(vd, o);
        }
        if (lane == 0) {
            as_[node] = vs;
            ad_[node] = vd;
        }
    }
}

// ---------------- per-dst segment softmax + weighted gather-sum ----------------
// One wave per node. Fast path (deg<=64): edge list fits one register chunk —
// softmax computed lane-parallel once, weights kept in registers, serial
// channel loop uses v_readlane broadcasts (no per-edge exp recompute).

__global__ __launch_bounds__(256) void agg_kernel(
        const float* __restrict__ hp,
        const float* __restrict__ as_, const float* __restrict__ ad_,
        const int* __restrict__ off, const int* __restrict__ csr_src,
        const float* __restrict__ bias, float* __restrict__ out, int n) {
    int t = threadIdx.x;
    int wave = t >> 6, lane = t & 63;
    int node = blockIdx.x * 4 + wave;
    if (node >= n) return;

    int beg = off[node], end = off[node + 1];
    int deg = end - beg;
    float adst = ad_[node];
    float e_self = leaky(as_[node] + adst);

    float acc;
    if (deg <= 64) {
        bool valid = lane < deg;
        int s = valid ? csr_src[beg + lane] : 0;
        float e = valid ? leaky(as_[s] + adst) : -3.4e38f;

        float m = e;
#pragma unroll
        for (int o = 32; o > 0; o >>= 1) m = fmaxf(m, __shfl_xor(m, o));
        m = fmaxf(m, e_self);

        float p = valid ? __expf(e - m) : 0.f;
        float pself = __expf(e_self - m);
        float se = p;
#pragma unroll
        for (int o = 32; o > 0; o >>= 1) se += __shfl_xor(se, o);
        se += pself;
        float inv = 1.0f / (se + 1e-16f);
        p *= inv;

        acc = pself * inv * hp[(size_t)node * 64 + lane];
        for (int j = 0; j < deg; ++j) {
            float w = bcast(p, j);
            int sj = bcast_i(s, j);
            acc = fmaf(w, hp[(size_t)sj * 64 + lane], acc);
        }
    } else {
        // generic fallback (rare): two strided passes + serial recompute
        float mymax = e_self;
        for (int i = beg + lane; i < end; i += 64) {
            int s = csr_src[i];
            mymax = fmaxf(mymax, leaky(as_[s] + adst));
        }
#pragma unroll
        for (int o = 32; o > 0; o >>= 1) mymax = fmaxf(mymax, __shfl_xor(mymax, o));
        float m = mymax;

        float se = 0.f;
        for (int i = beg + lane; i < end; i += 64) {
            int s = csr_src[i];
            se += __expf(leaky(as_[s] + adst) - m);
        }
#pragma unroll
        for (int o = 32; o > 0; o >>= 1) se += __shfl_xor(se, o);
        se += __expf(e_self - m);
        float inv = 1.0f / (se + 1e-16f);

        acc = __expf(e_self - m) * inv * hp[(size_t)node * 64 + lane];
        for (int i = beg; i < end; ++i) {
            int s = csr_src[i];
            float w = __expf(leaky(as_[s] + adst) - m) * inv;
            acc = fmaf(w, hp[(size_t)s * 64 + lane], acc);
        }
    }
    float r = acc + bias[lane];
    out[(size_t)node * 64 + lane] = r > 0.f ? r : 0.f;
}

// ---------------- launch ----------------

extern "C" void kernel_launch(void* const* d_in, const int* in_sizes, int n_in,
                              void* d_out, int out_size, void* d_ws, size_t ws_size,
                              hipStream_t stream) {
    const float* x = (const float*)d_in[0];
    const int* edge_index = (const int*)d_in[1];
    const int N = in_sizes[0] / 128;
    const int E = in_sizes[1] / 2;

    const float* W[3]    = {(const float*)d_in[4], (const float*)d_in[8],  (const float*)d_in[12]};
    const float* asrc[3] = {(const float*)d_in[5], (const float*)d_in[9],  (const float*)d_in[13]};
    const float* adst[3] = {(const float*)d_in[6], (const float*)d_in[10], (const float*)d_in[14]};
    const float* bias[3] = {(const float*)d_in[7], (const float*)d_in[11], (const float*)d_in[15]};

    char* ws = (char*)d_ws;
    size_t o = 0;
    auto alloc = [&](size_t bytes) {
        char* p = ws + o;
        o += (bytes + 255) & ~(size_t)255;
        return p;
    };
    const int nb = (N + SCAN_BLOCK - 1) / SCAN_BLOCK;
    int* deg       = (int*)alloc((size_t)N * 4);
    int* off       = (int*)alloc((size_t)(N + 1) * 4);
    int* cursor    = (int*)alloc((size_t)N * 4);
    int* csr_src   = (int*)alloc((size_t)E * 4);
    int* blockSums = (int*)alloc((size_t)nb * 4);
    int* blockOff  = (int*)alloc((size_t)nb * 4);
    float* as_     = (float*)alloc((size_t)N * 4);
    float* ad_     = (float*)alloc((size_t)N * 4);
    float* bufA    = (float*)alloc((size_t)N * 64 * 4);
    float* bufB    = (float*)alloc((size_t)N * 64 * 4);

    const int* srcp = edge_index;
    const int* dstp = edge_index + E;

    hipMemsetAsync(deg, 0, (size_t)N * 4, stream);
    hist_kernel<<<(E + 255) / 256, 256, 0, stream>>>(dstp, deg, E);
    block_reduce_kernel<<<nb, SCAN_BLOCK, 0, stream>>>(deg, blockSums, N);
    scan_sums_kernel<<<1, 256, 0, stream>>>(blockSums, blockOff, off, N, nb);
    write_offsets_kernel<<<nb, SCAN_BLOCK, 0, stream>>>(deg, blockOff, off, cursor, N);
    scatter_kernel<<<(E + 255) / 256, 256, 0, stream>>>(srcp, dstp, cursor, csr_src, E);

    const float* hin = x;
    for (int l = 0; l < 3; ++l) {
        float* hp = bufA;
        float* hout = (l == 2) ? (float*)d_out : bufB;
        if (l == 0) {
            gemm_alpha_kernel<128><<<(N + 31) / 32, 256, 0, stream>>>(
                hin, W[l], asrc[l], adst[l], hp, as_, ad_, N);
        } else {
            gemm_alpha_kernel<64><<<(N + 31) / 32, 256, 0, stream>>>(
                hin, W[l], asrc[l], adst[l], hp, as_, ad_, N);
        }
        agg_kernel<<<(N + 3) / 4, 256, 0, stream>>>(
            hp, as_, ad_, off, csr_src, bias[l], hout, N);
        hin = hout;
    }
}

// Round 5
// 388.713 us; speedup vs baseline: 1.8806x; 1.1866x over previous
//
#include <hip/hip_runtime.h>
#include <math.h>

#define NEG_SLOPE 0.2f
#define SCAN_BLOCK 512

__device__ __forceinline__ float leaky(float e) {
    return e > 0.f ? e : NEG_SLOPE * e;
}
__device__ __forceinline__ float bcast(float v, int j) {
    return __uint_as_float(__builtin_amdgcn_readlane(__float_as_uint(v), j));
}

// ---------------- CSR build ----------------

__global__ void hist_kernel(const int* __restrict__ dst, int* __restrict__ deg, int E) {
    int i = blockIdx.x * blockDim.x + threadIdx.x;
    if (i < E) atomicAdd(&deg[dst[i]], 1);
}

__global__ __launch_bounds__(SCAN_BLOCK) void block_reduce_kernel(
        const int* __restrict__ deg, int* __restrict__ blockSums, int n) {
    __shared__ int ws[SCAN_BLOCK / 64];
    int t = threadIdx.x;
    int i = blockIdx.x * SCAN_BLOCK + t;
    int v = (i < n) ? deg[i] : 0;
#pragma unroll
    for (int o = 32; o > 0; o >>= 1) v += __shfl_down(v, o);
    if ((t & 63) == 0) ws[t >> 6] = v;
    __syncthreads();
    if (t == 0) {
        int s = 0;
#pragma unroll
        for (int j = 0; j < SCAN_BLOCK / 64; ++j) s += ws[j];
        blockSums[blockIdx.x] = s;
    }
}

__global__ __launch_bounds__(256) void scan_sums_kernel(
        const int* __restrict__ blockSums, int* __restrict__ blockOff,
        int* __restrict__ off, int n, int nb) {
    __shared__ int s[256];
    int t = threadIdx.x;
    int v = (t < nb) ? blockSums[t] : 0;
    s[t] = v;
    __syncthreads();
    for (int o = 1; o < 256; o <<= 1) {
        int x = (t >= o) ? s[t - o] : 0;
        __syncthreads();
        s[t] += x;
        __syncthreads();
    }
    if (t < nb) blockOff[t] = s[t] - v;
    if (t == nb - 1) off[n] = s[t];
}

__global__ __launch_bounds__(SCAN_BLOCK) void write_offsets_kernel(
        const int* __restrict__ deg, const int* __restrict__ blockOff,
        int* __restrict__ off, int* __restrict__ cursor, int n) {
    __shared__ int s[SCAN_BLOCK];
    int t = threadIdx.x;
    int i = blockIdx.x * SCAN_BLOCK + t;
    int v = (i < n) ? deg[i] : 0;
    s[t] = v;
    __syncthreads();
    for (int o = 1; o < SCAN_BLOCK; o <<= 1) {
        int x = (t >= o) ? s[t - o] : 0;
        __syncthreads();
        s[t] += x;
        __syncthreads();
    }
    if (i < n) {
        int pos = blockOff[blockIdx.x] + s[t] - v;
        off[i] = pos;
        cursor[i] = pos;
    }
}

__global__ void scatter_kernel(const int* __restrict__ src, const int* __restrict__ dst,
                               int* __restrict__ cursor, int* __restrict__ csr_src, int E) {
    int i = blockIdx.x * blockDim.x + threadIdx.x;
    if (i < E) {
        int d = dst[i];
        int p = atomicAdd(&cursor[d], 1);
        csr_src[p] = src[i];
    }
}

// ---------------- GEMM + alpha epilogue ----------------

template <int CIN>
__global__ __launch_bounds__(256) void gemm_alpha_kernel(
        const float* __restrict__ h, const float* __restrict__ W,
        const float* __restrict__ a_src, const float* __restrict__ a_dst,
        float* __restrict__ hp, float* __restrict__ as_, float* __restrict__ ad_,
        int n) {
    constexpr int NPW = 8;
    constexpr int NC = CIN / 64;
    __shared__ float Ws[CIN * 64];
    int t = threadIdx.x, wave = t >> 6, lane = t & 63;
    int node0 = blockIdx.x * 32 + wave * NPW;

    {
        const float4* W4 = (const float4*)W;
        float4* Ws4 = (float4*)Ws;
        constexpr int cnt = CIN * 16;
#pragma unroll
        for (int i = 0; i < cnt / 256; ++i) Ws4[i * 256 + t] = W4[i * 256 + t];
    }

    float hreg[NPW][NC];
#pragma unroll
    for (int r = 0; r < NPW; ++r) {
        int node = node0 + r;
#pragma unroll
        for (int c = 0; c < NC; ++c)
            hreg[r][c] = (node < n) ? h[(size_t)node * CIN + c * 64 + lane] : 0.f;
    }
    __syncthreads();

    float acc[NPW];
#pragma unroll
    for (int r = 0; r < NPW; ++r) acc[r] = 0.f;

#pragma unroll
    for (int c = 0; c < NC; ++c) {
#pragma unroll 8
        for (int k2 = 0; k2 < 64; ++k2) {
            float w = Ws[(c * 64 + k2) * 64 + lane];
#pragma unroll
            for (int r = 0; r < NPW; ++r)
                acc[r] = fmaf(bcast(hreg[r][c], k2), w, acc[r]);
        }
    }

    float asl = a_src[lane], adl = a_dst[lane];
#pragma unroll
    for (int r = 0; r < NPW; ++r) {
        int node = node0 + r;
        if (node >= n) break;
        hp[(size_t)node * 64 + lane] = acc[r];
        float vs = acc[r] * asl;
        float vd = acc[r] * adl;
#pragma unroll
        for (int o = 32; o > 0; o >>= 1) {
            vs += __shfl_xor(vs, o);
            vd += __shfl_xor(vd, o);
        }
        if (lane == 0) {
            as_[node] = vs;
            ad_[node] = vd;
        }
    }
}

// ---------------- per-dst segment softmax + weighted gather-sum ----------------
// One wave per node. Fast path (deg<=64): softmax lane-parallel (converged
// shuffles only); normalized weights + src ids staged in per-wave LDS; gather
// loop = 4 lane-groups of 16, each loading one hp row as float4. Inside the
// (divergent-trip) gather loop only plain LDS/global loads — no cross-lane
// ops (a per-lane-index __shfl in a divergent loop miscompiled in R4).

__global__ __launch_bounds__(256) void agg_kernel(
        const float* __restrict__ hp,
        const float* __restrict__ as_, const float* __restrict__ ad_,
        const int* __restrict__ off, const int* __restrict__ csr_src,
        const float* __restrict__ bias, float* __restrict__ out, int n) {
    __shared__ float pw[4][64];
    __shared__ int ps[4][64];
    int t = threadIdx.x;
    int wave = t >> 6, lane = t & 63;
    int node = blockIdx.x * 4 + wave;
    if (node >= n) return;

    int beg = off[node], end = off[node + 1];
    int deg = end - beg;
    float adst = ad_[node];
    float e_self = leaky(as_[node] + adst);

    if (deg <= 64) {
        bool valid = lane < deg;
        int s = valid ? csr_src[beg + lane] : 0;
        float e = valid ? leaky(as_[s] + adst) : -3.4e38f;

        float m = e;
#pragma unroll
        for (int o = 32; o > 0; o >>= 1) m = fmaxf(m, __shfl_xor(m, o));
        m = fmaxf(m, e_self);

        float p = valid ? __expf(e - m) : 0.f;
        float pself = __expf(e_self - m);
        float se = p;
#pragma unroll
        for (int o = 32; o > 0; o >>= 1) se += __shfl_xor(se, o);
        se += pself;
        float inv = 1.0f / (se + 1e-16f);
        p *= inv;

        // stage per-edge weight + src id in this wave's LDS scratch
        // (same-wave produce/consume: LDS pipe is in-order per wave, no barrier)
        pw[wave][lane] = p;
        ps[wave][lane] = s;

        int group = lane >> 4, sub = lane & 15;
        const float4* hp4 = (const float4*)hp;

        float wself = (group == 0) ? pself * inv : 0.f;
        float4 hv = hp4[(size_t)node * 16 + sub];
        float4 acc;
        acc.x = wself * hv.x;
        acc.y = wself * hv.y;
        acc.z = wself * hv.z;
        acc.w = wself * hv.w;

        for (int j = group; j < deg; j += 4) {
            float w = pw[wave][j];
            int sj = ps[wave][j];
            float4 v = hp4[(size_t)sj * 16 + sub];
            acc.x = fmaf(w, v.x, acc.x);
            acc.y = fmaf(w, v.y, acc.y);
            acc.z = fmaf(w, v.z, acc.z);
            acc.w = fmaf(w, v.w, acc.w);
        }

        // all lanes reconverged here — xor-tree across the 4 groups
#pragma unroll
        for (int o = 16; o <= 32; o <<= 1) {
            acc.x += __shfl_xor(acc.x, o);
            acc.y += __shfl_xor(acc.y, o);
            acc.z += __shfl_xor(acc.z, o);
            acc.w += __shfl_xor(acc.w, o);
        }

        float4 b4 = ((const float4*)bias)[sub];
        float4 r;
        r.x = acc.x + b4.x; r.x = r.x > 0.f ? r.x : 0.f;
        r.y = acc.y + b4.y; r.y = r.y > 0.f ? r.y : 0.f;
        r.z = acc.z + b4.z; r.z = r.z > 0.f ? r.z : 0.f;
        r.w = acc.w + b4.w; r.w = r.w > 0.f ? r.w : 0.f;
        if (group == 0) ((float4*)out)[(size_t)node * 16 + sub] = r;
    } else {
        // generic fallback (rare)
        float mymax = e_self;
        for (int i = beg + lane; i < end; i += 64) {
            int s = csr_src[i];
            mymax = fmaxf(mymax, leaky(as_[s] + adst));
        }
#pragma unroll
        for (int o = 32; o > 0; o >>= 1) mymax = fmaxf(mymax, __shfl_xor(mymax, o));
        float m = mymax;

        float se = 0.f;
        for (int i = beg + lane; i < end; i += 64) {
            int s = csr_src[i];
            se += __expf(leaky(as_[s] + adst) - m);
        }
#pragma unroll
        for (int o = 32; o > 0; o >>= 1) se += __shfl_xor(se, o);
        se += __expf(e_self - m);
        float inv = 1.0f / (se + 1e-16f);

        float acc = __expf(e_self - m) * inv * hp[(size_t)node * 64 + lane];
        for (int i = beg; i < end; ++i) {
            int s = csr_src[i];
            float w = __expf(leaky(as_[s] + adst) - m) * inv;
            acc = fmaf(w, hp[(size_t)s * 64 + lane], acc);
        }
        float r = acc + bias[lane];
        out[(size_t)node * 64 + lane] = r > 0.f ? r : 0.f;
    }
}

// ---------------- launch ----------------

extern "C" void kernel_launch(void* const* d_in, const int* in_sizes, int n_in,
                              void* d_out, int out_size, void* d_ws, size_t ws_size,
                              hipStream_t stream) {
    const float* x = (const float*)d_in[0];
    const int* edge_index = (const int*)d_in[1];
    const int N = in_sizes[0] / 128;
    const int E = in_sizes[1] / 2;

    const float* W[3]    = {(const float*)d_in[4], (const float*)d_in[8],  (const float*)d_in[12]};
    const float* asrc[3] = {(const float*)d_in[5], (const float*)d_in[9],  (const float*)d_in[13]};
    const float* adst[3] = {(const float*)d_in[6], (const float*)d_in[10], (const float*)d_in[14]};
    const float* bias[3] = {(const float*)d_in[7], (const float*)d_in[11], (const float*)d_in[15]};

    char* ws = (char*)d_ws;
    size_t o = 0;
    auto alloc = [&](size_t bytes) {
        char* p = ws + o;
        o += (bytes + 255) & ~(size_t)255;
        return p;
    };
    const int nb = (N + SCAN_BLOCK - 1) / SCAN_BLOCK;
    int* deg       = (int*)alloc((size_t)N * 4);
    int* off       = (int*)alloc((size_t)(N + 1) * 4);
    int* cursor    = (int*)alloc((size_t)N * 4);
    int* csr_src   = (int*)alloc((size_t)E * 4);
    int* blockSums = (int*)alloc((size_t)nb * 4);
    int* blockOff  = (int*)alloc((size_t)nb * 4);
    float* as_     = (float*)alloc((size_t)N * 4);
    float* ad_     = (float*)alloc((size_t)N * 4);
    float* bufA    = (float*)alloc((size_t)N * 64 * 4);
    float* bufB    = (float*)alloc((size_t)N * 64 * 4);

    const int* srcp = edge_index;
    const int* dstp = edge_index + E;

    hipMemsetAsync(deg, 0, (size_t)N * 4, stream);
    hist_kernel<<<(E + 255) / 256, 256, 0, stream>>>(dstp, deg, E);
    block_reduce_kernel<<<nb, SCAN_BLOCK, 0, stream>>>(deg, blockSums, N);
    scan_sums_kernel<<<1, 256, 0, stream>>>(blockSums, blockOff, off, N, nb);
    write_offsets_kernel<<<nb, SCAN_BLOCK, 0, stream>>>(deg, blockOff, off, cursor, N);
    scatter_kernel<<<(E + 255) / 256, 256, 0, stream>>>(srcp, dstp, cursor, csr_src, E);

    const float* hin = x;
    for (int l = 0; l < 3; ++l) {
        float* hp = bufA;
        float* hout = (l == 2) ? (float*)d_out : bufB;
        if (l == 0) {
            gemm_alpha_kernel<128><<<(N + 31) / 32, 256, 0, stream>>>(
                hin, W[l], asrc[l], adst[l], hp, as_, ad_, N);
        } else {
            gemm_alpha_kernel<64><<<(N + 31) / 32, 256, 0, stream>>>(
                hin, W[l], asrc[l], adst[l], hp, as_, ad_, N);
        }
        agg_kernel<<<(N + 3) / 4, 256, 0, stream>>>(
            hp, as_, ad_, off, csr_src, bias[l], hout, N);
        hin = hout;
    }
}

// Round 6
// 341.720 us; speedup vs baseline: 2.1392x; 1.1375x over previous
//
#include <hip/hip_runtime.h>
#include <math.h>

#define NEG_SLOPE 0.2f
#define BSHIFT 8            // nodes per bucket = 256 (requires N < 65536 for src packing)

__device__ __forceinline__ float leaky(float e) {
    return e > 0.f ? e : NEG_SLOPE * e;
}
__device__ __forceinline__ float bcast(float v, int j) {
    return __uint_as_float(__builtin_amdgcn_readlane(__float_as_uint(v), j));
}

// ---------------- CSR build: bucketed counting sort ----------------
// Bucket b covers nodes [b<<8, (b+1)<<8). Edge payload packed as
// (src << 8) | (dst & 255)  — src < 65536 fits; bucket id implied by position.

__global__ __launch_bounds__(256) void bucket_count_kernel(
        const int* __restrict__ dst, int* __restrict__ bucketCnt, int E, int nbk) {
    __shared__ int cnt[256];
    int t = threadIdx.x;
    cnt[t] = 0;
    __syncthreads();
    for (int i = blockIdx.x * 256 + t; i < E; i += gridDim.x * 256)
        atomicAdd(&cnt[dst[i] >> BSHIFT], 1);
    __syncthreads();
    if (t < nbk && cnt[t] > 0) atomicAdd(&bucketCnt[t], cnt[t]);
}

__global__ __launch_bounds__(256) void bucket_scan_kernel(
        const int* __restrict__ bucketCnt, int* __restrict__ bucketOff,
        int* __restrict__ bucketCursor, int nbk) {
    __shared__ int s[256];
    int t = threadIdx.x;
    int v = (t < nbk) ? bucketCnt[t] : 0;
    s[t] = v;
    __syncthreads();
    for (int o = 1; o < 256; o <<= 1) {
        int x = (t >= o) ? s[t - o] : 0;
        __syncthreads();
        s[t] += x;
        __syncthreads();
    }
    if (t < nbk) {
        int excl = s[t] - v;
        bucketOff[t] = excl;
        bucketCursor[t] = excl;
    }
}

__global__ __launch_bounds__(256) void partition_kernel(
        const int* __restrict__ src, const int* __restrict__ dst,
        int* __restrict__ bucketCursor, int* __restrict__ pairs, int E, int nbk) {
    __shared__ int cnt[256];
    __shared__ int run[256];
    int t = threadIdx.x;
    int chunk = (E + gridDim.x - 1) / gridDim.x;
    int beg = blockIdx.x * chunk;
    int end = min(beg + chunk, E);
    cnt[t] = 0;
    __syncthreads();
    for (int i = beg + t; i < end; i += 256)
        atomicAdd(&cnt[dst[i] >> BSHIFT], 1);
    __syncthreads();
    if (t < nbk) run[t] = atomicAdd(&bucketCursor[t], cnt[t]);
    __syncthreads();
    for (int i = beg + t; i < end; i += 256) {
        int d = dst[i];
        int slot = atomicAdd(&run[d >> BSHIFT], 1);
        pairs[slot] = (src[i] << BSHIFT) | (d & 255);
    }
}

// one block per bucket: per-node LDS histogram + scan + local cursor scatter.
// Block exclusively owns its contiguous csr_src region — no line sharing.
__global__ __launch_bounds__(256) void csr_build_kernel(
        const int* __restrict__ bucketOff, const int* __restrict__ pairs,
        int* __restrict__ off, int* __restrict__ csr_src, int N, int E, int nbk) {
    __shared__ int degl[256];
    __shared__ int s[256];
    __shared__ int cur[256];
    int t = threadIdx.x;
    int b = blockIdx.x;
    int n0 = b << BSHIFT;
    int nodecnt = min(256, N - n0);
    int ebeg = bucketOff[b];
    int eend = (b == nbk - 1) ? E : bucketOff[b + 1];

    degl[t] = 0;
    __syncthreads();
    for (int i = ebeg + t; i < eend; i += 256)
        atomicAdd(&degl[pairs[i] & 255], 1);
    __syncthreads();

    int v = degl[t];
    s[t] = v;
    __syncthreads();
    for (int o = 1; o < 256; o <<= 1) {
        int x = (t >= o) ? s[t - o] : 0;
        __syncthreads();
        s[t] += x;
        __syncthreads();
    }
    int excl = s[t] - v;
    if (t < nodecnt) off[n0 + t] = ebeg + excl;
    if (b == 0 && t == 0) off[N] = E;
    cur[t] = excl;
    __syncthreads();

    for (int i = ebeg + t; i < eend; i += 256) {
        int pk = pairs[i];
        int p = atomicAdd(&cur[pk & 255], 1);
        csr_src[ebeg + p] = pk >> BSHIFT;
    }
}

// ---------------- GEMM + alpha epilogue ----------------

template <int CIN>
__global__ __launch_bounds__(256) void gemm_alpha_kernel(
        const float* __restrict__ h, const float* __restrict__ W,
        const float* __restrict__ a_src, const float* __restrict__ a_dst,
        float* __restrict__ hp, float* __restrict__ as_, float* __restrict__ ad_,
        int n) {
    constexpr int NPW = 8;
    constexpr int NC = CIN / 64;
    __shared__ float Ws[CIN * 64];
    int t = threadIdx.x, wave = t >> 6, lane = t & 63;
    int node0 = blockIdx.x * 32 + wave * NPW;

    {
        const float4* W4 = (const float4*)W;
        float4* Ws4 = (float4*)Ws;
        constexpr int cnt = CIN * 16;
#pragma unroll
        for (int i = 0; i < cnt / 256; ++i) Ws4[i * 256 + t] = W4[i * 256 + t];
    }

    float hreg[NPW][NC];
#pragma unroll
    for (int r = 0; r < NPW; ++r) {
        int node = node0 + r;
#pragma unroll
        for (int c = 0; c < NC; ++c)
            hreg[r][c] = (node < n) ? h[(size_t)node * CIN + c * 64 + lane] : 0.f;
    }
    __syncthreads();

    float acc[NPW];
#pragma unroll
    for (int r = 0; r < NPW; ++r) acc[r] = 0.f;

#pragma unroll
    for (int c = 0; c < NC; ++c) {
#pragma unroll 8
        for (int k2 = 0; k2 < 64; ++k2) {
            float w = Ws[(c * 64 + k2) * 64 + lane];
#pragma unroll
            for (int r = 0; r < NPW; ++r)
                acc[r] = fmaf(bcast(hreg[r][c], k2), w, acc[r]);
        }
    }

    float asl = a_src[lane], adl = a_dst[lane];
#pragma unroll
    for (int r = 0; r < NPW; ++r) {
        int node = node0 + r;
        if (node >= n) break;
        hp[(size_t)node * 64 + lane] = acc[r];
        float vs = acc[r] * asl;
        float vd = acc[r] * adl;
#pragma unroll
        for (int o = 32; o > 0; o >>= 1) {
            vs += __shfl_xor(vs, o);
            vd += __shfl_xor(vd, o);
        }
        if (lane == 0) {
            as_[node] = vs;
            ad_[node] = vd;
        }
    }
}

// ---------------- per-dst segment softmax + weighted gather-sum ----------------
// One wave per node. NO cross-lane ops inside divergent-trip loops (R4 trap).

__global__ __launch_bounds__(256) void agg_kernel(
        const float* __restrict__ hp,
        const float* __restrict__ as_, const float* __restrict__ ad_,
        const int* __restrict__ off, const int* __restrict__ csr_src,
        const float* __restrict__ bias, float* __restrict__ out, int n) {
    __shared__ float pw[4][64];
    __shared__ int ps[4][64];
    int t = threadIdx.x;
    int wave = t >> 6, lane = t & 63;
    int node = blockIdx.x * 4 + wave;
    if (node >= n) return;

    int beg = off[node], end = off[node + 1];
    int deg = end - beg;
    float adst = ad_[node];
    float e_self = leaky(as_[node] + adst);

    if (deg <= 64) {
        bool valid = lane < deg;
        int s = valid ? csr_src[beg + lane] : 0;
        float e = valid ? leaky(as_[s] + adst) : -3.4e38f;

        float m = e;
#pragma unroll
        for (int o = 32; o > 0; o >>= 1) m = fmaxf(m, __shfl_xor(m, o));
        m = fmaxf(m, e_self);

        float p = valid ? __expf(e - m) : 0.f;
        float pself = __expf(e_self - m);
        float se = p;
#pragma unroll
        for (int o = 32; o > 0; o >>= 1) se += __shfl_xor(se, o);
        se += pself;
        float inv = 1.0f / (se + 1e-16f);
        p *= inv;

        pw[wave][lane] = p;
        ps[wave][lane] = s;

        int group = lane >> 4, sub = lane & 15;
        const float4* hp4 = (const float4*)hp;

        float wself = (group == 0) ? pself * inv : 0.f;
        float4 hv = hp4[(size_t)node * 16 + sub];
        float4 acc;
        acc.x = wself * hv.x;
        acc.y = wself * hv.y;
        acc.z = wself * hv.z;
        acc.w = wself * hv.w;

        for (int j = group; j < deg; j += 4) {
            float w = pw[wave][j];
            int sj = ps[wave][j];
            float4 v = hp4[(size_t)sj * 16 + sub];
            acc.x = fmaf(w, v.x, acc.x);
            acc.y = fmaf(w, v.y, acc.y);
            acc.z = fmaf(w, v.z, acc.z);
            acc.w = fmaf(w, v.w, acc.w);
        }

#pragma unroll
        for (int o = 16; o <= 32; o <<= 1) {
            acc.x += __shfl_xor(acc.x, o);
            acc.y += __shfl_xor(acc.y, o);
            acc.z += __shfl_xor(acc.z, o);
            acc.w += __shfl_xor(acc.w, o);
        }

        float4 b4 = ((const float4*)bias)[sub];
        float4 r;
        r.x = acc.x + b4.x; r.x = r.x > 0.f ? r.x : 0.f;
        r.y = acc.y + b4.y; r.y = r.y > 0.f ? r.y : 0.f;
        r.z = acc.z + b4.z; r.z = r.z > 0.f ? r.z : 0.f;
        r.w = acc.w + b4.w; r.w = r.w > 0.f ? r.w : 0.f;
        if (group == 0) ((float4*)out)[(size_t)node * 16 + sub] = r;
    } else {
        float mymax = e_self;
        for (int i = beg + lane; i < end; i += 64) {
            int s = csr_src[i];
            mymax = fmaxf(mymax, leaky(as_[s] + adst));
        }
#pragma unroll
        for (int o = 32; o > 0; o >>= 1) mymax = fmaxf(mymax, __shfl_xor(mymax, o));
        float m = mymax;

        float se = 0.f;
        for (int i = beg + lane; i < end; i += 64) {
            int s = csr_src[i];
            se += __expf(leaky(as_[s] + adst) - m);
        }
#pragma unroll
        for (int o = 32; o > 0; o >>= 1) se += __shfl_xor(se, o);
        se += __expf(e_self - m);
        float inv = 1.0f / (se + 1e-16f);

        float acc = __expf(e_self - m) * inv * hp[(size_t)node * 64 + lane];
        for (int i = beg; i < end; ++i) {
            int s = csr_src[i];
            float w = __expf(leaky(as_[s] + adst) - m) * inv;
            acc = fmaf(w, hp[(size_t)s * 64 + lane], acc);
        }
        float r = acc + bias[lane];
        out[(size_t)node * 64 + lane] = r > 0.f ? r : 0.f;
    }
}

// ---------------- launch ----------------

extern "C" void kernel_launch(void* const* d_in, const int* in_sizes, int n_in,
                              void* d_out, int out_size, void* d_ws, size_t ws_size,
                              hipStream_t stream) {
    const float* x = (const float*)d_in[0];
    const int* edge_index = (const int*)d_in[1];
    const int N = in_sizes[0] / 128;
    const int E = in_sizes[1] / 2;
    const int NBK = (N + 255) >> BSHIFT;   // 196 buckets for N=50000; requires NBK<=256

    const float* W[3]    = {(const float*)d_in[4], (const float*)d_in[8],  (const float*)d_in[12]};
    const float* asrc[3] = {(const float*)d_in[5], (const float*)d_in[9],  (const float*)d_in[13]};
    const float* adst[3] = {(const float*)d_in[6], (const float*)d_in[10], (const float*)d_in[14]};
    const float* bias[3] = {(const float*)d_in[7], (const float*)d_in[11], (const float*)d_in[15]};

    char* ws = (char*)d_ws;
    size_t o = 0;
    auto alloc = [&](size_t bytes) {
        char* p = ws + o;
        o += (bytes + 255) & ~(size_t)255;
        return p;
    };
    int* bucketCnt    = (int*)alloc(256 * 4);
    int* bucketOff    = (int*)alloc(257 * 4);
    int* bucketCursor = (int*)alloc(256 * 4);
    int* pairs        = (int*)alloc((size_t)E * 4);
    int* off          = (int*)alloc((size_t)(N + 1) * 4);
    int* csr_src      = (int*)alloc((size_t)E * 4);
    float* as_        = (float*)alloc((size_t)N * 4);
    float* ad_        = (float*)alloc((size_t)N * 4);
    float* bufA       = (float*)alloc((size_t)N * 64 * 4);
    float* bufB       = (float*)alloc((size_t)N * 64 * 4);

    const int* srcp = edge_index;
    const int* dstp = edge_index + E;

    hipMemsetAsync(bucketCnt, 0, 256 * 4, stream);
    bucket_count_kernel<<<256, 256, 0, stream>>>(dstp, bucketCnt, E, NBK);
    bucket_scan_kernel<<<1, 256, 0, stream>>>(bucketCnt, bucketOff, bucketCursor, NBK);
    partition_kernel<<<256, 256, 0, stream>>>(srcp, dstp, bucketCursor, pairs, E, NBK);
    csr_build_kernel<<<NBK, 256, 0, stream>>>(bucketOff, pairs, off, csr_src, N, E, NBK);

    const float* hin = x;
    for (int l = 0; l < 3; ++l) {
        float* hp = bufA;
        float* hout = (l == 2) ? (float*)d_out : bufB;
        if (l == 0) {
            gemm_alpha_kernel<128><<<(N + 31) / 32, 256, 0, stream>>>(
                hin, W[l], asrc[l], adst[l], hp, as_, ad_, N);
        } else {
            gemm_alpha_kernel<64><<<(N + 31) / 32, 256, 0, stream>>>(
                hin, W[l], asrc[l], adst[l], hp, as_, ad_, N);
        }
        agg_kernel<<<(N + 3) / 4, 256, 0, stream>>>(
            hp, as_, ad_, off, csr_src, bias[l], hout, N);
        hin = hout;
    }
}